// Round 8
// baseline (174.293 us; speedup 1.0000x reference)
//
#include <hip/hip_runtime.h>

#define NROW 4096
#define DIM  512
#define NT   32   // 4096 / 128 tiles per dimension

using short8 = __attribute__((ext_vector_type(8))) short;
using f32x4  = __attribute__((ext_vector_type(4))) float;

__device__ __forceinline__ unsigned short f2bf(float f) {
  unsigned u = __float_as_uint(f);
  u += 0x7FFFu + ((u >> 16) & 1u);          // round-to-nearest-even
  return (unsigned short)(u >> 16);
}
__device__ __forceinline__ float bf2f(unsigned short s) {
  return __uint_as_float(((unsigned)s) << 16);
}

// ---------- prep: fp32 -> bf16 bits, row squared norms, zero accumulators ----------
__global__ void __launch_bounds__(256) prep_kernel(
    const float* __restrict__ X, const float* __restrict__ Y,
    unsigned short* __restrict__ Xb, unsigned short* __restrict__ Yb,
    float* __restrict__ sqx, float* __restrict__ sqy,
    float* __restrict__ acc /* rK[4096] rL[4096] S1 cnt */) {
  int tid = threadIdx.x;
  if (blockIdx.x == 0) {
    for (int i = tid; i < 2 * NROW + 2; i += 256) acc[i] = 0.f;
  }
  int lane = tid & 63, w = tid >> 6;
  int row = blockIdx.x * 4 + w;

  {
    const float* xr = X + (size_t)row * DIM;
    unsigned short* xo = Xb + (size_t)row * DIM;
    float s = 0.f;
#pragma unroll
    for (int it = 0; it < 2; ++it) {
      int k = it * 256 + lane * 4;
      float4 v = *reinterpret_cast<const float4*>(xr + k);
      ushort4 o;
      o.x = f2bf(v.x); o.y = f2bf(v.y); o.z = f2bf(v.z); o.w = f2bf(v.w);
      float f0 = bf2f(o.x), f1 = bf2f(o.y), f2 = bf2f(o.z), f3 = bf2f(o.w);
      s += f0 * f0 + f1 * f1 + f2 * f2 + f3 * f3;
      *reinterpret_cast<ushort4*>(xo + k) = o;
    }
#pragma unroll
    for (int m = 1; m < 64; m <<= 1) s += __shfl_xor(s, m);
    if (lane == 0) sqx[row] = s;
  }
  {
    const float* yr = Y + (size_t)row * DIM;
    unsigned short* yo = Yb + (size_t)row * DIM;
    float s = 0.f;
#pragma unroll
    for (int it = 0; it < 2; ++it) {
      int k = it * 256 + lane * 4;
      float4 v = *reinterpret_cast<const float4*>(yr + k);
      ushort4 o;
      o.x = f2bf(v.x); o.y = f2bf(v.y); o.z = f2bf(v.z); o.w = f2bf(v.w);
      float f0 = bf2f(o.x), f1 = bf2f(o.y), f2 = bf2f(o.z), f3 = bf2f(o.w);
      s += f0 * f0 + f1 * f1 + f2 * f2 + f3 * f3;
      *reinterpret_cast<ushort4*>(yo + k) = o;
    }
#pragma unroll
    for (int m = 1; m < 64; m <<= 1) s += __shfl_xor(s, m);
    if (lane == 0) sqy[row] = s;
  }
}

// ---------- staging: global_load_lds width=16, linear LDS dest, ----------
// ---------- inverse-swizzled global source (rule #21 / T2)      ----------
__device__ __forceinline__ void stage_tile(unsigned short* lds,
                                           const unsigned short* gbase, // src + row0*DIM + k0
                                           int gt) {                    // tid within 256-thr group
  int w = gt >> 6;
#pragma unroll
  for (int p = 0; p < 4; ++p) {
    int q = p * 256 + gt;        // 16B chunk id, 0..1023 (128 rows x 8 chunks)
    int r = q >> 3;              // tile row
    int c = q & 7;               // chunk-in-row at the linear LDS slot
    int cs = c ^ (r & 7);        // source chunk (involution)
    const unsigned short* gp = gbase + r * DIM + cs * 8;
    unsigned short* lp = lds + (p * 256 + w * 64) * 8;  // wave-uniform base, +lane*16B by HW
    __builtin_amdgcn_global_load_lds(
        (const __attribute__((address_space(1))) void*)gp,
        (__attribute__((address_space(3))) void*)lp, 16, 0, 0);
  }
}

// 32 MFMAs on one staged (A,B) tile pair (K=64), swizzled ds_read_b128
__device__ __forceinline__ void tile_mfma(const unsigned short* At, const unsigned short* Bt,
                                          int lr, int lgq, int wr, int wc,
                                          f32x4 acc[4][4]) {
#pragma unroll
  for (int kk = 0; kk < 2; ++kk) {
    short8 a[4], b[4];
#pragma unroll
    for (int m = 0; m < 4; ++m) {
      int ra = wr * 64 + m * 16 + lr;
      int ca = kk * 4 + lgq;
      a[m] = *reinterpret_cast<const short8*>(At + (ra * 8 + (ca ^ (ra & 7))) * 8);
      int rb = wc * 64 + m * 16 + lr;
      b[m] = *reinterpret_cast<const short8*>(Bt + (rb * 8 + (ca ^ (rb & 7))) * 8);
    }
#pragma unroll
    for (int m = 0; m < 4; ++m)
#pragma unroll
      for (int n = 0; n < 4; ++n)
        acc[m][n] = __builtin_amdgcn_mfma_f32_16x16x32_bf16(a[m], b[n], acc[m][n], 0, 0, 0);
  }
}

// ---------- gram: 8-wave gram-split blocks; waves 0-3 -> X gram, waves 4-7 -> Y gram.
// Single-buffered per-group LDS (2 x 32KB), 8 K-steps, fused RBF epilogue,
// last-block finalize via done-counter.
__global__ void __launch_bounds__(512, 4) gram_kernel(
    const unsigned short* __restrict__ Xb, const unsigned short* __restrict__ Yb,
    const float* __restrict__ sqx, const float* __restrict__ sqy,
    float* __restrict__ accbuf, float* __restrict__ out) {
  __shared__ union SM {
    unsigned short stage[2][2][128 * 64];   // [group][A|B] 64 KB
    float lx[128 * 132];                    // padded L-tile exchange (67.6 KB)
  } sm;
  __shared__ float s1buf[4];
  __shared__ int lastf;
  __shared__ float fin[3][8];

  float* rKg = accbuf;
  float* rLg = accbuf + NROW;
  float* S1g = accbuf + 2 * NROW;
  unsigned int* cnt = (unsigned int*)(accbuf + 2 * NROW + 1);

  int tid = threadIdx.x;
  int g    = tid >> 8;          // gram group: 0 = X/K, 1 = Y/L
  int gt   = tid & 255;         // tid within group
  int lane = tid & 63;
  int gw   = (tid >> 6) & 3;    // wave within group
  int wr = gw >> 1, wc = gw & 1;
  int lr = lane & 15, lgq = lane >> 4;

  // XCD-aware bijective swizzle: 528 blocks = 8 XCDs x 66
  int wg = (blockIdx.x & 7) * 66 + (blockIdx.x >> 3);
  int t = wg, bi = 0;
  while (t >= NT - bi) { t -= NT - bi; ++bi; }
  int bj = bi + t;

  const unsigned short* src = g ? Yb : Xb;
  const float* sq = g ? sqy : sqx;
  float* racc = g ? rLg : rKg;

  unsigned short* tA = sm.stage[g][0];
  unsigned short* tB = sm.stage[g][1];
  const size_t rowA = (size_t)(bi * 128) * DIM;
  const size_t rowB = (size_t)(bj * 128) * DIM;

  f32x4 acc[4][4];
  f32x4 zz = {0.f, 0.f, 0.f, 0.f};
#pragma unroll
  for (int m = 0; m < 4; ++m)
#pragma unroll
    for (int n = 0; n < 4; ++n) acc[m][n] = zz;

  for (int kb = 0; kb < 8; ++kb) {
    stage_tile(tA, src + rowA + kb * 64, gt);
    stage_tile(tB, src + rowB + kb * 64, gt);
    __syncthreads();
    tile_mfma(tA, tB, lr, lgq, wr, wc, acc);
    __syncthreads();
  }

  // ---- epilogue pass 1 (both groups): v = exp(-d2/2) in-place; row/col sums;
  // ---- group 1 also publishes L-values to LDS.
  float colsum[4] = {0.f, 0.f, 0.f, 0.f};
  int cj[4]; float sj[4];
#pragma unroll
  for (int n = 0; n < 4; ++n) {
    cj[n] = wc * 64 + n * 16 + lr;          // local col in tile
    sj[n] = sq[bj * 128 + cj[n]];
  }
#pragma unroll
  for (int m = 0; m < 4; ++m) {
#pragma unroll
    for (int r = 0; r < 4; ++r) {
      int ri = wr * 64 + m * 16 + lgq * 4 + r;  // local row (C layout: row=(lane>>4)*4+reg)
      float si = sq[bi * 128 + ri];
      float rowsum = 0.f;
#pragma unroll
      for (int n = 0; n < 4; ++n) {
        float d = acc[m][n][r];
        float v;
        if (bi * 128 + ri == bj * 128 + cj[n]) v = 1.f;   // exact diagonal
        else v = __expf(-0.5f * fmaxf(si + sj[n] - 2.f * d, 0.f));
        acc[m][n][r] = v;
        rowsum += v; colsum[n] += v;
        if (g) sm.lx[ri * 132 + cj[n]] = v;
      }
#pragma unroll
      for (int msk = 1; msk < 16; msk <<= 1) rowsum += __shfl_xor(rowsum, msk);
      if (lr == 0) atomicAdd(&racc[bi * 128 + ri], rowsum);
    }
  }
  if (bi != bj) {
#pragma unroll
    for (int n = 0; n < 4; ++n) {
      float a = colsum[n];
      a += __shfl_xor(a, 16); a += __shfl_xor(a, 32);
      if (lgq == 0) atomicAdd(&racc[bj * 128 + cj[n]], a);
    }
  }

  __syncthreads();   // lx fully written

  // ---- epilogue pass 2 (group 0): S1 = sum kv*lv ----
  if (g == 0) {
    float s1 = 0.f;
#pragma unroll
    for (int m = 0; m < 4; ++m)
#pragma unroll
      for (int r = 0; r < 4; ++r) {
        int ri = wr * 64 + m * 16 + lgq * 4 + r;
#pragma unroll
        for (int n = 0; n < 4; ++n)
          s1 += acc[m][n][r] * sm.lx[ri * 132 + cj[n]];
      }
    if (bi != bj) s1 *= 2.f;
#pragma unroll
    for (int msk = 1; msk < 64; msk <<= 1) s1 += __shfl_xor(s1, msk);
    if (lane == 0) s1buf[gw] = s1;
  }
  __syncthreads();
  if (tid == 0) atomicAdd(S1g, s1buf[0] + s1buf[1] + s1buf[2] + s1buf[3]);

  // ---- done-counter: last block finalizes ----
  __threadfence();
  __syncthreads();
  if (tid == 0) lastf = (atomicAdd(cnt, 1u) == (unsigned)(NT * (NT + 1) / 2 - 1));
  __syncthreads();
  if (!lastf) return;

  __threadfence();
  float sk = 0.f, sl = 0.f, s2 = 0.f;
  int base = tid * 8;
#pragma unroll
  for (int i = 0; i < 8; ++i) {
    float a = __hip_atomic_load(rKg + base + i, __ATOMIC_RELAXED, __HIP_MEMORY_SCOPE_AGENT);
    float b = __hip_atomic_load(rLg + base + i, __ATOMIC_RELAXED, __HIP_MEMORY_SCOPE_AGENT);
    sk += a; sl += b; s2 += a * b;
  }
#pragma unroll
  for (int msk = 1; msk < 64; msk <<= 1) {
    sk += __shfl_xor(sk, msk);
    sl += __shfl_xor(sl, msk);
    s2 += __shfl_xor(s2, msk);
  }
  int w8 = tid >> 6;
  if (lane == 0) { fin[0][w8] = sk; fin[1][w8] = sl; fin[2][w8] = s2; }
  __syncthreads();
  if (tid == 0) {
    double SK = 0.0, SL = 0.0, S2 = 0.0;
#pragma unroll
    for (int i = 0; i < 8; ++i) { SK += fin[0][i]; SL += fin[1][i]; S2 += fin[2][i]; }
    double s1v = (double)__hip_atomic_load(S1g, __ATOMIC_RELAXED, __HIP_MEMORY_SCOPE_AGENT);
    double n = (double)NROW;
    out[0] = (float)((s1v - 2.0 * S2 / n + SK * SL / (n * n)) / (n * n));
  }
}

extern "C" void kernel_launch(void* const* d_in, const int* in_sizes, int n_in,
                              void* d_out, int out_size, void* d_ws, size_t ws_size,
                              hipStream_t stream) {
  (void)in_sizes; (void)n_in; (void)out_size; (void)ws_size;
  const float* X = (const float*)d_in[0];
  const float* Y = (const float*)d_in[1];

  unsigned short* Xb = (unsigned short*)d_ws;                 // 4 MB
  unsigned short* Yb = Xb + (size_t)NROW * DIM;               // 4 MB
  float* sqx = (float*)(Yb + (size_t)NROW * DIM);             // 16 KB
  float* sqy = sqx + NROW;                                    // 16 KB
  float* acc = sqy + NROW;                                    // rK | rL | S1 | cnt

  prep_kernel<<<NROW / 4, 256, 0, stream>>>(X, Y, Xb, Yb, sqx, sqy, acc);
  gram_kernel<<<NT * (NT + 1) / 2, 512, 0, stream>>>(Xb, Yb, sqx, sqy,
                                                     acc, (float*)d_out);
}

// Round 11
// 148.772 us; speedup vs baseline: 1.1715x; 1.1715x over previous
//
#include <hip/hip_runtime.h>
#include <hip/hip_fp8.h>

#define NROW 4096
#define DIM  512
#define NT   32   // 4096 / 128 tiles per dimension

using f32x4 = __attribute__((ext_vector_type(4))) float;

// ---------- prep: fp32 -> fp8 e4m3 (OCP), row sq-norms of ROUNDED values, zero accum ----------
__global__ void __launch_bounds__(256) prep_kernel(
    const float* __restrict__ X, const float* __restrict__ Y,
    unsigned char* __restrict__ Xq, unsigned char* __restrict__ Yq,
    float* __restrict__ sqx, float* __restrict__ sqy,
    float* __restrict__ acc /* rK[4096] rL[4096] S1 cnt */) {
  int tid = threadIdx.x;
  if (blockIdx.x == 0) {
    for (int i = tid; i < 2 * NROW + 2; i += 256) acc[i] = 0.f;
  }
  int lane = tid & 63, w = tid >> 6;
  int row = blockIdx.x * 4 + w;

  {
    const float* xr = X + (size_t)row * DIM;
    unsigned char* xo = Xq + (size_t)row * DIM;
    float s = 0.f;
#pragma unroll
    for (int it = 0; it < 2; ++it) {
      int k = it * 256 + lane * 4;
      float4 v = *reinterpret_cast<const float4*>(xr + k);
      __hip_fp8_e4m3 q0(v.x), q1(v.y), q2(v.z), q3(v.w);
      uchar4 o = make_uchar4(q0.__x, q1.__x, q2.__x, q3.__x);
      float f0 = (float)q0, f1 = (float)q1, f2 = (float)q2, f3 = (float)q3;
      s += f0 * f0 + f1 * f1 + f2 * f2 + f3 * f3;
      *reinterpret_cast<uchar4*>(xo + k) = o;
    }
#pragma unroll
    for (int m = 1; m < 64; m <<= 1) s += __shfl_xor(s, m);
    if (lane == 0) sqx[row] = s;
  }
  {
    const float* yr = Y + (size_t)row * DIM;
    unsigned char* yo = Yq + (size_t)row * DIM;
    float s = 0.f;
#pragma unroll
    for (int it = 0; it < 2; ++it) {
      int k = it * 256 + lane * 4;
      float4 v = *reinterpret_cast<const float4*>(yr + k);
      __hip_fp8_e4m3 q0(v.x), q1(v.y), q2(v.z), q3(v.w);
      uchar4 o = make_uchar4(q0.__x, q1.__x, q2.__x, q3.__x);
      float f0 = (float)q0, f1 = (float)q1, f2 = (float)q2, f3 = (float)q3;
      s += f0 * f0 + f1 * f1 + f2 * f2 + f3 * f3;
      *reinterpret_cast<uchar4*>(yo + k) = o;
    }
#pragma unroll
    for (int m = 1; m < 64; m <<= 1) s += __shfl_xor(s, m);
    if (lane == 0) sqy[row] = s;
  }
}

// ---------- staging: fp8 tile 128 rows x 64 B = 8 KB = 512 x 16B chunks ----------
// linear LDS dest (rule #21), inverse-swizzled global source, involution c ^ (r&3)
__device__ __forceinline__ void stage_tile(unsigned char* lds,
                                           const unsigned char* gbase, // src + row0*DIM + kb*64
                                           int tid) {
  int w = tid >> 6;
#pragma unroll
  for (int p = 0; p < 2; ++p) {
    int q = p * 256 + tid;       // chunk id 0..511 (128 rows x 4 chunks)
    int r = q >> 2;              // tile row
    int c = q & 3;               // chunk-in-row at linear LDS slot
    int cs = c ^ (r & 3);        // source chunk (involution)
    const unsigned char* gp = gbase + r * DIM + cs * 16;
    unsigned char* lp = lds + (p * 256 + w * 64) * 16;  // wave-uniform base, +lane*16B by HW
    __builtin_amdgcn_global_load_lds(
        (const __attribute__((address_space(1))) void*)gp,
        (__attribute__((address_space(3))) void*)lp, 16, 0, 0);
  }
}

// 32 MFMAs (fp8 16x16x32) on one staged (A,B) tile pair (K=64), swizzled ds_read_b64
__device__ __forceinline__ void tile_mfma(const unsigned char* At, const unsigned char* Bt,
                                          int lr, int lgq, int wr, int wc,
                                          f32x4 acc[4][4]) {
#pragma unroll
  for (int kk = 0; kk < 2; ++kk) {
    long a[4], b[4];
    int ca8 = kk * 4 + lgq;      // 8-byte K-group 0..7
    int cc = ca8 >> 1, h = ca8 & 1;
#pragma unroll
    for (int m = 0; m < 4; ++m) {
      int ra = wr * 64 + m * 16 + lr;
      a[m] = *reinterpret_cast<const long*>(At + ra * 64 + ((cc ^ (ra & 3)) << 4) + (h << 3));
      int rb = wc * 64 + m * 16 + lr;
      b[m] = *reinterpret_cast<const long*>(Bt + rb * 64 + ((cc ^ (rb & 3)) << 4) + (h << 3));
    }
#pragma unroll
    for (int m = 0; m < 4; ++m)
#pragma unroll
      for (int n = 0; n < 4; ++n)
        acc[m][n] = __builtin_amdgcn_mfma_f32_16x16x32_fp8_fp8(a[m], b[n], acc[m][n], 0, 0, 0);
  }
}

// ---------- gram: dual Gram (upper triangle), fp8 staging, dbuf + prefetch (R4 structure),
// fused RBF epilogue + done-counter finalize ----------
__global__ void __launch_bounds__(256, 2) gram_kernel(
    const unsigned char* __restrict__ Xq, const unsigned char* __restrict__ Yq,
    const float* __restrict__ sqx, const float* __restrict__ sqy,
    float* __restrict__ accbuf, float* __restrict__ out) {
  __shared__ unsigned char lds[2][2][128 * 64];   // [buf][A|B] = 32 KB
  __shared__ float s1buf[4];
  __shared__ int lastf;
  __shared__ float fin[3][4];

  float* rK = accbuf;
  float* rL = accbuf + NROW;
  float* S1 = accbuf + 2 * NROW;
  unsigned int* cnt = (unsigned int*)(accbuf + 2 * NROW + 1);

  int tid = threadIdx.x;
  // XCD-aware bijective swizzle: 528 blocks = 8 XCDs x 66
  int wg = (blockIdx.x & 7) * 66 + (blockIdx.x >> 3);
  int t = wg, bi = 0;
  while (t >= NT - bi) { t -= NT - bi; ++bi; }
  int bj = bi + t;

  int lane = tid & 63, w = tid >> 6;
  int wr = w >> 1, wc = w & 1;
  int lr = lane & 15, lgq = lane >> 4;

  f32x4 accK[4][4], accL[4][4];
  f32x4 zz = {0.f, 0.f, 0.f, 0.f};
#pragma unroll
  for (int m = 0; m < 4; ++m)
#pragma unroll
    for (int n = 0; n < 4; ++n) { accK[m][n] = zz; accL[m][n] = zz; }

  const size_t rowA = (size_t)(bi * 128) * DIM;   // bytes (1 B/elem)
  const size_t rowB = (size_t)(bj * 128) * DIM;

  auto stage_pair = [&](int it) {   // it 0..15: it>>3 selects X/Y, it&7 selects K-block
    const unsigned char* src = (it & 8) ? Yq : Xq;
    int kb = it & 7;
    stage_tile(lds[it & 1][0], src + rowA + kb * 64, tid);
    stage_tile(lds[it & 1][1], src + rowB + kb * 64, tid);
  };

  stage_pair(0);
  __syncthreads();
#pragma unroll
  for (int kb = 0; kb < 8; ++kb) {            // X gram; prefetch next (incl. Y kb0 at kb=7)
    stage_pair(kb + 1);
    tile_mfma(lds[kb & 1][0], lds[kb & 1][1], lr, lgq, wr, wc, accK);
    __syncthreads();
  }
#pragma unroll
  for (int kb = 0; kb < 8; ++kb) {            // Y gram
    if (kb < 7) stage_pair(8 + kb + 1);
    tile_mfma(lds[kb & 1][0], lds[kb & 1][1], lr, lgq, wr, wc, accL);
    __syncthreads();
  }

  // ---- epilogue: k = exp(-d2/2), fused S1 / row sums / symmetric col sums ----
  float ckx[4] = {0.f, 0.f, 0.f, 0.f};
  float cky[4] = {0.f, 0.f, 0.f, 0.f};
  float sjx[4], sjy[4]; int gj[4];
#pragma unroll
  for (int n = 0; n < 4; ++n) {
    gj[n] = bj * 128 + wc * 64 + n * 16 + lr;
    sjx[n] = sqx[gj[n]];
    sjy[n] = sqy[gj[n]];
  }
  float s1loc = 0.f;
#pragma unroll
  for (int m = 0; m < 4; ++m) {
#pragma unroll
    for (int r = 0; r < 4; ++r) {
      int gi = bi * 128 + wr * 64 + m * 16 + lgq * 4 + r;   // C layout: row=(lane>>4)*4+reg
      float six = sqx[gi], siy = sqy[gi];
      float rowk = 0.f, rowl = 0.f;
#pragma unroll
      for (int n = 0; n < 4; ++n) {
        float gk = accK[m][n][r];
        float gl = accL[m][n][r];
        float kv, lv;
        if (gi == gj[n]) { kv = 1.f; lv = 1.f; }             // exact diagonal
        else {
          kv = __expf(-0.5f * fmaxf(six + sjx[n] - 2.f * gk, 0.f));
          lv = __expf(-0.5f * fmaxf(siy + sjy[n] - 2.f * gl, 0.f));
        }
        s1loc += kv * lv;
        rowk += kv; rowl += lv;
        ckx[n] += kv; cky[n] += lv;
      }
#pragma unroll
      for (int msk = 1; msk < 16; msk <<= 1) {
        rowk += __shfl_xor(rowk, msk);
        rowl += __shfl_xor(rowl, msk);
      }
      if (lr == 0) { atomicAdd(&rK[gi], rowk); atomicAdd(&rL[gi], rowl); }
    }
  }
  if (bi != bj) {
#pragma unroll
    for (int n = 0; n < 4; ++n) {
      float a = ckx[n], b = cky[n];
      a += __shfl_xor(a, 16); a += __shfl_xor(a, 32);
      b += __shfl_xor(b, 16); b += __shfl_xor(b, 32);
      if (lgq == 0) { atomicAdd(&rK[gj[n]], a); atomicAdd(&rL[gj[n]], b); }
    }
    s1loc *= 2.f;
  }
#pragma unroll
  for (int msk = 1; msk < 64; msk <<= 1) s1loc += __shfl_xor(s1loc, msk);
  if (lane == 0) s1buf[w] = s1loc;
  __syncthreads();
  if (tid == 0) atomicAdd(S1, s1buf[0] + s1buf[1] + s1buf[2] + s1buf[3]);

  // ---- done-counter: last block finalizes ----
  __threadfence();
  __syncthreads();
  if (tid == 0) lastf = (atomicAdd(cnt, 1u) == (unsigned)(NT * (NT + 1) / 2 - 1));
  __syncthreads();
  if (!lastf) return;

  __threadfence();
  float sk = 0.f, sl = 0.f, s2 = 0.f;
  int base = tid * 16;
#pragma unroll
  for (int i = 0; i < 16; ++i) {
    float a = __hip_atomic_load(rK + base + i, __ATOMIC_RELAXED, __HIP_MEMORY_SCOPE_AGENT);
    float b = __hip_atomic_load(rL + base + i, __ATOMIC_RELAXED, __HIP_MEMORY_SCOPE_AGENT);
    sk += a; sl += b; s2 += a * b;
  }
#pragma unroll
  for (int msk = 1; msk < 64; msk <<= 1) {
    sk += __shfl_xor(sk, msk);
    sl += __shfl_xor(sl, msk);
    s2 += __shfl_xor(s2, msk);
  }
  if (lane == 0) { fin[0][w] = sk; fin[1][w] = sl; fin[2][w] = s2; }
  __syncthreads();
  if (tid == 0) {
    double SK = 0.0, SL = 0.0, S2 = 0.0;
#pragma unroll
    for (int i = 0; i < 4; ++i) { SK += fin[0][i]; SL += fin[1][i]; S2 += fin[2][i]; }
    double s1v = (double)__hip_atomic_load(S1, __ATOMIC_RELAXED, __HIP_MEMORY_SCOPE_AGENT);
    double n = (double)NROW;
    out[0] = (float)((s1v - 2.0 * S2 / n + SK * SL / (n * n)) / (n * n));
  }
}

extern "C" void kernel_launch(void* const* d_in, const int* in_sizes, int n_in,
                              void* d_out, int out_size, void* d_ws, size_t ws_size,
                              hipStream_t stream) {
  (void)in_sizes; (void)n_in; (void)out_size; (void)ws_size;
  const float* X = (const float*)d_in[0];
  const float* Y = (const float*)d_in[1];

  unsigned char* Xq = (unsigned char*)d_ws;                  // 2 MB
  unsigned char* Yq = Xq + (size_t)NROW * DIM;               // 2 MB
  float* sqx = (float*)(Yq + (size_t)NROW * DIM);            // 16 KB
  float* sqy = sqx + NROW;                                   // 16 KB
  float* acc = sqy + NROW;                                   // rK | rL | S1 | cnt

  prep_kernel<<<NROW / 4, 256, 0, stream>>>(X, Y, Xq, Yq, sqx, sqy, acc);
  gram_kernel<<<NT * (NT + 1) / 2, 256, 0, stream>>>(Xq, Yq, sqx, sqy,
                                                     acc, (float*)d_out);
}

// Round 12
// 134.763 us; speedup vs baseline: 1.2933x; 1.1039x over previous
//
#include <hip/hip_runtime.h>

#define NROW 4096
#define DIM  512
#define NT   32    // 4096 / 128 tiles per dimension
#define NPAIR 528  // NT*(NT+1)/2
#define NBLK  264  // 2 pairs per block, 8 XCDs x 33

using short8 = __attribute__((ext_vector_type(8))) short;
using f32x4  = __attribute__((ext_vector_type(4))) float;

__device__ __forceinline__ unsigned short f2bf(float f) {
  unsigned u = __float_as_uint(f);
  u += 0x7FFFu + ((u >> 16) & 1u);          // round-to-nearest-even
  return (unsigned short)(u >> 16);
}
__device__ __forceinline__ float bf2f(unsigned short s) {
  return __uint_as_float(((unsigned)s) << 16);
}

// ---------- prep: fp32 -> bf16 bits, row squared norms, zero accumulators ----------
__global__ void __launch_bounds__(256) prep_kernel(
    const float* __restrict__ X, const float* __restrict__ Y,
    unsigned short* __restrict__ Xb, unsigned short* __restrict__ Yb,
    float* __restrict__ sqx, float* __restrict__ sqy,
    float* __restrict__ acc /* rK[4096] rL[4096] S1 cnt */) {
  int tid = threadIdx.x;
  if (blockIdx.x == 0) {
    for (int i = tid; i < 2 * NROW + 2; i += 256) acc[i] = 0.f;
  }
  int lane = tid & 63, w = tid >> 6;
  int row = blockIdx.x * 4 + w;

  {
    const float* xr = X + (size_t)row * DIM;
    unsigned short* xo = Xb + (size_t)row * DIM;
    float s = 0.f;
#pragma unroll
    for (int it = 0; it < 2; ++it) {
      int k = it * 256 + lane * 4;
      float4 v = *reinterpret_cast<const float4*>(xr + k);
      ushort4 o;
      o.x = f2bf(v.x); o.y = f2bf(v.y); o.z = f2bf(v.z); o.w = f2bf(v.w);
      float f0 = bf2f(o.x), f1 = bf2f(o.y), f2 = bf2f(o.z), f3 = bf2f(o.w);
      s += f0 * f0 + f1 * f1 + f2 * f2 + f3 * f3;
      *reinterpret_cast<ushort4*>(xo + k) = o;
    }
#pragma unroll
    for (int m = 1; m < 64; m <<= 1) s += __shfl_xor(s, m);
    if (lane == 0) sqx[row] = s;
  }
  {
    const float* yr = Y + (size_t)row * DIM;
    unsigned short* yo = Yb + (size_t)row * DIM;
    float s = 0.f;
#pragma unroll
    for (int it = 0; it < 2; ++it) {
      int k = it * 256 + lane * 4;
      float4 v = *reinterpret_cast<const float4*>(yr + k);
      ushort4 o;
      o.x = f2bf(v.x); o.y = f2bf(v.y); o.z = f2bf(v.z); o.w = f2bf(v.w);
      float f0 = bf2f(o.x), f1 = bf2f(o.y), f2 = bf2f(o.z), f3 = bf2f(o.w);
      s += f0 * f0 + f1 * f1 + f2 * f2 + f3 * f3;
      *reinterpret_cast<ushort4*>(yo + k) = o;
    }
#pragma unroll
    for (int m = 1; m < 64; m <<= 1) s += __shfl_xor(s, m);
    if (lane == 0) sqy[row] = s;
  }
}

// ---------- staging: global_load_lds width=16, linear LDS dest, ----------
// ---------- inverse-swizzled global source (rule #21 / T2)      ----------
__device__ __forceinline__ void stage_tile(unsigned short* lds,
                                           const unsigned short* gbase, // src + row0*DIM + k0
                                           int tid) {
  int w = tid >> 6;
#pragma unroll
  for (int p = 0; p < 4; ++p) {
    int q = p * 256 + tid;       // 16B chunk id, 0..1023 (128 rows x 8 chunks)
    int r = q >> 3;              // tile row
    int c = q & 7;               // chunk-in-row at the linear LDS slot
    int cs = c ^ (r & 7);        // source chunk (involution)
    const unsigned short* gp = gbase + r * DIM + cs * 8;
    unsigned short* lp = lds + (p * 256 + w * 64) * 8;  // wave-uniform base, +lane*16B by HW
    __builtin_amdgcn_global_load_lds(
        (const __attribute__((address_space(1))) void*)gp,
        (__attribute__((address_space(3))) void*)lp, 16, 0, 0);
  }
}

// 32 MFMAs on one staged (A,B) tile pair (K=64), swizzled ds_read_b128
__device__ __forceinline__ void tile_mfma(const unsigned short* At, const unsigned short* Bt,
                                          int lr, int lgq, int wr, int wc,
                                          f32x4 acc[4][4]) {
#pragma unroll
  for (int kk = 0; kk < 2; ++kk) {
    short8 a[4], b[4];
#pragma unroll
    for (int m = 0; m < 4; ++m) {
      int ra = wr * 64 + m * 16 + lr;
      int ca = kk * 4 + lgq;
      a[m] = *reinterpret_cast<const short8*>(At + (ra * 8 + (ca ^ (ra & 7))) * 8);
      int rb = wc * 64 + m * 16 + lr;
      b[m] = *reinterpret_cast<const short8*>(Bt + (rb * 8 + (ca ^ (rb & 7))) * 8);
    }
#pragma unroll
    for (int m = 0; m < 4; ++m)
#pragma unroll
      for (int n = 0; n < 4; ++n)
        acc[m][n] = __builtin_amdgcn_mfma_f32_16x16x32_bf16(a[m], b[n], acc[m][n], 0, 0, 0);
  }
}

// ---------- gram: 2 tile-pairs per block (balanced, zero-tail grid), bf16,
// dbuf + counted-vmcnt pipeline (T4), fused RBF epilogue + done-counter finalize ----------
__global__ void __launch_bounds__(256, 2) gram_kernel(
    const unsigned short* __restrict__ Xb, const unsigned short* __restrict__ Yb,
    const float* __restrict__ sqx, const float* __restrict__ sqy,
    float* __restrict__ accbuf, float* __restrict__ out) {
  __shared__ unsigned short lds[2][2][128 * 64];   // [buf][A|B] = 64 KB
  __shared__ float s1buf[4];
  __shared__ int lastf;
  __shared__ float fin[3][4];

  float* rK = accbuf;
  float* rL = accbuf + NROW;
  float* S1 = accbuf + 2 * NROW;
  unsigned int* cnt = (unsigned int*)(accbuf + 2 * NROW + 1);

  int tid = threadIdx.x;
  int lane = tid & 63, w = tid >> 6;
  int wr = w >> 1, wc = w & 1;
  int lr = lane & 15, lgq = lane >> 4;

  // XCD-aware bijective swizzle: 264 blocks = 8 XCDs x 33
  int wg = (blockIdx.x & 7) * 33 + (blockIdx.x >> 3);

  for (int pp = 0; pp < 2; ++pp) {
    // decode upper-triangular tile pair
    int t = wg * 2 + pp, bi = 0;
    while (t >= NT - bi) { t -= NT - bi; ++bi; }
    int bj = bi + t;

    f32x4 accK[4][4], accL[4][4];
    f32x4 zz = {0.f, 0.f, 0.f, 0.f};
#pragma unroll
    for (int m = 0; m < 4; ++m)
#pragma unroll
      for (int n = 0; n < 4; ++n) { accK[m][n] = zz; accL[m][n] = zz; }

    const size_t rowA = (size_t)(bi * 128) * DIM;
    const size_t rowB = (size_t)(bj * 128) * DIM;

    auto stage_pair = [&](int it) {   // it 0..15: it>>3 selects X/Y, it&7 selects K-block
      const unsigned short* src = (it & 8) ? Yb : Xb;
      int kb = it & 7;
      stage_tile(lds[it & 1][0], src + rowA + kb * 64, tid);
      stage_tile(lds[it & 1][1], src + rowB + kb * 64, tid);
    };

    stage_pair(0);                                  // 8 loads in flight
#pragma unroll
    for (int st = 0; st < 16; ++st) {
      if (st < 15) {
        stage_pair(st + 1);                         // +8 loads (other buffer)
        asm volatile("s_waitcnt vmcnt(8)" ::: "memory");   // drain current batch ONLY
      } else {
        asm volatile("s_waitcnt vmcnt(0)" ::: "memory");
      }
      __builtin_amdgcn_s_barrier();                 // all waves' batch landed
      __builtin_amdgcn_sched_barrier(0);            // pin ds_reads below barrier (rule #18)
      tile_mfma(lds[st & 1][0], lds[st & 1][1], lr, lgq, wr, wc,
                (st < 8) ? accK : accL);
      __builtin_amdgcn_s_barrier();                 // protect buffer reuse
    }

    // ---- epilogue: k = exp(-d2/2), fused S1 / row sums / symmetric col sums ----
    float ckx[4] = {0.f, 0.f, 0.f, 0.f};
    float cky[4] = {0.f, 0.f, 0.f, 0.f};
    float sjx[4], sjy[4]; int gj[4];
#pragma unroll
    for (int n = 0; n < 4; ++n) {
      gj[n] = bj * 128 + wc * 64 + n * 16 + lr;
      sjx[n] = sqx[gj[n]];
      sjy[n] = sqy[gj[n]];
    }
    float s1loc = 0.f;
#pragma unroll
    for (int m = 0; m < 4; ++m) {
#pragma unroll
      for (int r = 0; r < 4; ++r) {
        int gi = bi * 128 + wr * 64 + m * 16 + lgq * 4 + r;  // C layout: row=(lane>>4)*4+reg
        float six = sqx[gi], siy = sqy[gi];
        float rowk = 0.f, rowl = 0.f;
#pragma unroll
        for (int n = 0; n < 4; ++n) {
          float gk = accK[m][n][r];
          float gl = accL[m][n][r];
          float kv, lv;
          if (gi == gj[n]) { kv = 1.f; lv = 1.f; }           // exact diagonal
          else {
            kv = __expf(-0.5f * fmaxf(six + sjx[n] - 2.f * gk, 0.f));
            lv = __expf(-0.5f * fmaxf(siy + sjy[n] - 2.f * gl, 0.f));
          }
          s1loc += kv * lv;
          rowk += kv; rowl += lv;
          ckx[n] += kv; cky[n] += lv;
        }
#pragma unroll
        for (int msk = 1; msk < 16; msk <<= 1) {
          rowk += __shfl_xor(rowk, msk);
          rowl += __shfl_xor(rowl, msk);
        }
        if (lr == 0) { atomicAdd(&rK[gi], rowk); atomicAdd(&rL[gi], rowl); }
      }
    }
    if (bi != bj) {
#pragma unroll
      for (int n = 0; n < 4; ++n) {
        float a = ckx[n], b = cky[n];
        a += __shfl_xor(a, 16); a += __shfl_xor(a, 32);
        b += __shfl_xor(b, 16); b += __shfl_xor(b, 32);
        if (lgq == 0) { atomicAdd(&rK[gj[n]], a); atomicAdd(&rL[gj[n]], b); }
      }
      s1loc *= 2.f;
    }
#pragma unroll
    for (int msk = 1; msk < 64; msk <<= 1) s1loc += __shfl_xor(s1loc, msk);
    if (lane == 0) s1buf[w] = s1loc;
    __syncthreads();
    if (tid == 0) atomicAdd(S1, s1buf[0] + s1buf[1] + s1buf[2] + s1buf[3]);
  }

  // ---- done-counter: last block finalizes ----
  __threadfence();
  __syncthreads();
  if (tid == 0) lastf = (atomicAdd(cnt, 1u) == (unsigned)(NBLK - 1));
  __syncthreads();
  if (!lastf) return;

  __threadfence();
  float sk = 0.f, sl = 0.f, s2 = 0.f;
  int base = tid * 16;
#pragma unroll
  for (int i = 0; i < 16; ++i) {
    float a = __hip_atomic_load(rK + base + i, __ATOMIC_RELAXED, __HIP_MEMORY_SCOPE_AGENT);
    float b = __hip_atomic_load(rL + base + i, __ATOMIC_RELAXED, __HIP_MEMORY_SCOPE_AGENT);
    sk += a; sl += b; s2 += a * b;
  }
#pragma unroll
  for (int msk = 1; msk < 64; msk <<= 1) {
    sk += __shfl_xor(sk, msk);
    sl += __shfl_xor(sl, msk);
    s2 += __shfl_xor(s2, msk);
  }
  if (lane == 0) { fin[0][w] = sk; fin[1][w] = sl; fin[2][w] = s2; }
  __syncthreads();
  if (tid == 0) {
    double SK = 0.0, SL = 0.0, S2 = 0.0;
#pragma unroll
    for (int i = 0; i < 4; ++i) { SK += fin[0][i]; SL += fin[1][i]; S2 += fin[2][i]; }
    double s1v = (double)__hip_atomic_load(S1, __ATOMIC_RELAXED, __HIP_MEMORY_SCOPE_AGENT);
    double n = (double)NROW;
    out[0] = (float)((s1v - 2.0 * S2 / n + SK * SL / (n * n)) / (n * n));
  }
}

extern "C" void kernel_launch(void* const* d_in, const int* in_sizes, int n_in,
                              void* d_out, int out_size, void* d_ws, size_t ws_size,
                              hipStream_t stream) {
  (void)in_sizes; (void)n_in; (void)out_size; (void)ws_size;
  const float* X = (const float*)d_in[0];
  const float* Y = (const float*)d_in[1];

  unsigned short* Xb = (unsigned short*)d_ws;                 // 4 MB
  unsigned short* Yb = Xb + (size_t)NROW * DIM;               // 4 MB
  float* sqx = (float*)(Yb + (size_t)NROW * DIM);             // 16 KB
  float* sqy = sqx + NROW;                                    // 16 KB
  float* acc = sqy + NROW;                                    // rK | rL | S1 | cnt

  prep_kernel<<<NROW / 4, 256, 0, stream>>>(X, Y, Xb, Yb, sqx, sqy, acc);
  gram_kernel<<<NBLK, 256, 0, stream>>>(Xb, Yb, sqx, sqy, acc, (float*)d_out);
}